// Round 23
// baseline (951.222 us; speedup 1.0000x reference)
//
#include <hip/hip_runtime.h>

#define NB    8
#define NH    16384
#define NL    2048
#define F_HR  64
#define F_LR  128
#define OUT_COLS 198   // 64 + 3 + 128 + 3
#define NC    16       // grid cells per axis
#define NC3   4096

// ---------------------------------------------------------------------------
// Prep kernel (8 blocks, 1 per batch): counting-sort candidates into a 16^3
// grid. Box = per-axis min/max of pos_lr (all candidates provably in-box).
// halfsq text identical to all passing rounds: 0.5f*((x*x+y*y)+z*z).
// Outputs (d_ws): scand float4[8*2048], sorig int[8*2048],
//                 cstart int[8*4097], hdr float[8*12] {bmin3,invh3,h3,hmin}.
// ---------------------------------------------------------------------------
__global__ __launch_bounds__(256) void prep_kernel(
    const float* __restrict__ pos_lr,
    float4* __restrict__ scand, int* __restrict__ sorig,
    int* __restrict__ cstart, float* __restrict__ hdr)
{
    __shared__ int   cnt[NC3];      // 16 KB: counts -> starts
    __shared__ int   cur[NC3];      // 16 KB: scatter cursors
    __shared__ int   parts[256];
    __shared__ float red[256];
    __shared__ float sbmin[3], sh[3], sinvh[3];

    const int b = blockIdx.x;
    const int tid = threadIdx.x;
    const float* pl = pos_lr + (size_t)b * NL * 3;

    // per-axis min/max
    float mn[3] = {1e30f, 1e30f, 1e30f}, mx[3] = {-1e30f, -1e30f, -1e30f};
    for (int j = tid; j < NL; j += 256) {
#pragma unroll
        for (int a = 0; a < 3; ++a) {
            const float v = pl[j * 3 + a];
            mn[a] = fminf(mn[a], v);
            mx[a] = fmaxf(mx[a], v);
        }
    }
#pragma unroll
    for (int a = 0; a < 3; ++a) {
        red[tid] = mn[a]; __syncthreads();
        for (int s = 128; s > 0; s >>= 1) {
            if (tid < s) red[tid] = fminf(red[tid], red[tid + s]);
            __syncthreads();
        }
        if (tid == 0) sbmin[a] = red[0];
        __syncthreads();
        red[tid] = mx[a]; __syncthreads();
        for (int s = 128; s > 0; s >>= 1) {
            if (tid < s) red[tid] = fmaxf(red[tid], red[tid + s]);
            __syncthreads();
        }
        if (tid == 0) {
            const float h = (red[0] - sbmin[a]) * (1.0001f / NC) + 1e-7f;
            sh[a] = h; sinvh[a] = 1.0f / h;
        }
        __syncthreads();
    }

    // zero counts
    for (int c = tid; c < NC3; c += 256) cnt[c] = 0;
    __syncthreads();

    // count
    for (int j = tid; j < NL; j += 256) {
        const float x = pl[j * 3 + 0], y = pl[j * 3 + 1], z = pl[j * 3 + 2];
        int ix = min(max((int)((x - sbmin[0]) * sinvh[0]), 0), NC - 1);
        int iy = min(max((int)((y - sbmin[1]) * sinvh[1]), 0), NC - 1);
        int iz = min(max((int)((z - sbmin[2]) * sinvh[2]), 0), NC - 1);
        atomicAdd(&cnt[(iz * NC + iy) * NC + ix], 1);
    }
    __syncthreads();

    // prefix sum: 16 cells per thread -> 256 partials -> serial scan -> starts
    {
        const int base = tid * 16;
        int s = 0;
#pragma unroll
        for (int i = 0; i < 16; ++i) s += cnt[base + i];
        parts[tid] = s;
    }
    __syncthreads();
    if (tid == 0) {
        int run = 0;
        for (int i = 0; i < 256; ++i) { const int v = parts[i]; parts[i] = run; run += v; }
    }
    __syncthreads();
    {
        const int base = tid * 16;
        int run = parts[tid];
#pragma unroll
        for (int i = 0; i < 16; ++i) {
            const int v = cnt[base + i];
            cnt[base + i] = run;
            cur[base + i] = run;
            run += v;
        }
    }
    __syncthreads();

    // write cell starts + header
    for (int c = tid; c < NC3; c += 256) cstart[b * (NC3 + 1) + c] = cnt[c];
    if (tid == 0) cstart[b * (NC3 + 1) + NC3] = NL;
    if (tid < 3) {
        hdr[b * 12 + tid]     = sbmin[tid];
        hdr[b * 12 + 3 + tid] = sinvh[tid];
        hdr[b * 12 + 6 + tid] = sh[tid];
    }
    if (tid == 9) hdr[b * 12 + 9] = fminf(sh[0], fminf(sh[1], sh[2]));

    // scatter (same cid arithmetic as count phase)
    for (int j = tid; j < NL; j += 256) {
        const float x = pl[j * 3 + 0], y = pl[j * 3 + 1], z = pl[j * 3 + 2];
        int ix = min(max((int)((x - sbmin[0]) * sinvh[0]), 0), NC - 1);
        int iy = min(max((int)((y - sbmin[1]) * sinvh[1]), 0), NC - 1);
        int iz = min(max((int)((z - sbmin[2]) * sinvh[2]), 0), NC - 1);
        const int pos = atomicAdd(&cur[(iz * NC + iy) * NC + ix], 1);
        scand[b * NL + pos] = make_float4(x, y, z, 0.5f * ((x * x + y * y) + z * z));
        sorig[b * NL + pos] = j;
    }
}

// ---------------------------------------------------------------------------
// Fused main kernel. Blocks [0,512): grid-pruned knn (1 lane = 1 point) +
// gather of cols 67..197. Blocks [512,1024): idx-independent copy.
// Exactness: key d = identical fmaf chain (bit-exact across 18 rounds);
// selection (d<best take; d==best -> min ORIGINAL index) is visit-order-
// independent = first-occurrence. Ring bound conservative: prune ring r only
// if ((r-1)*hmin - excess)^2 > (2*best+qsq)*1.0001 + 1e-3; r<=16 covers the
// whole grid regardless, so termination never misses a candidate.
// LDS ~50KB -> 3 blocks/CU.
// ---------------------------------------------------------------------------
__global__ __launch_bounds__(256) void fused_kernel(
    const float* __restrict__ pos_hr,   // [NB*NH, 3]
    const float* __restrict__ pos_lr,   // [NB*NL, 3]
    const float* __restrict__ x_hr,     // [NB*NH, 64]
    const float* __restrict__ x_lr,     // [NB*NL, 128]
    const float4* __restrict__ scand,
    const int* __restrict__ sorig,
    const int* __restrict__ cstart,
    const float* __restrict__ hdr,
    float* __restrict__ out)
{
    __shared__ float4 cand4[NL];        // 32 KB sorted candidates
    __shared__ int    cstartL[NC3 + 1]; // 16.0 KB
    __shared__ int    s_idx[256];       //  1 KB winner (global lr row)
    __shared__ float  shdr[12];

    const int tid = threadIdx.x;

    if (blockIdx.x < 512) {
        // ----------------------------- knn role -----------------------------
        const int b  = blockIdx.x >> 6;     // 64 blocks per batch
        const int p0 = blockIdx.x << 8;     // 256 points per block

        for (int j = tid; j < NL; j += 256)       cand4[j]   = scand[b * NL + j];
        for (int j = tid; j < NC3 + 1; j += 256)  cstartL[j] = cstart[b * (NC3 + 1) + j];
        if (tid < 12) shdr[tid] = hdr[b * 12 + tid];
        __syncthreads();

        const float qx = pos_hr[(p0 + tid) * 3 + 0];
        const float qy = pos_hr[(p0 + tid) * 3 + 1];
        const float qz = pos_hr[(p0 + tid) * 3 + 2];
        const float qsq = (qx * qx + qy * qy) + qz * qz;

        const float bx = shdr[0], by = shdr[1], bz = shdr[2];
        const float ivx = shdr[3], ivy = shdr[4], ivz = shdr[5];
        const float hx = shdr[6], hy = shdr[7], hz = shdr[8];
        const float hmin = shdr[9];

        const int icx = min(max((int)((qx - bx) * ivx), 0), NC - 1);
        const int icy = min(max((int)((qy - by) * ivy), 0), NC - 1);
        const int icz = min(max((int)((qz - bz) * ivz), 0), NC - 1);
        const float excess = fmaxf(0.0f, fmaxf(
            fmaxf(bx - qx, qx - (bx + NC * hx)),
            fmaxf(fmaxf(by - qy, qy - (by + NC * hy)),
                  fmaxf(bz - qz, qz - (bz + NC * hz)))));

        float best = 3.4e38f;
        int   bk = 0;                       // sorted pos of current winner
        int   borig = 0x7FFFFFFF;           // lazy original-index (ties only)
        bool  done = false;

        for (int r = 0; r <= NC; ++r) {
            if (!done && r > 0) {
                const float lb = (float)(r - 1) * hmin - excess;
                if (lb > 0.0f) {
                    const float d2b = fmaf(2.0f, best, qsq);
                    if (lb * lb > d2b * 1.0001f + 1e-3f) done = true;
                }
            }
            if (__ballot(!done) == 0ull) break;
            if (!done) {
                for (int dz = -r; dz <= r; ++dz) {
                    const int iz = icz + dz;
                    if (iz < 0 || iz >= NC) continue;
                    const bool ez = (dz == r) || (dz == -r);
                    for (int dy = -r; dy <= r; ++dy) {
                        const int iy = icy + dy;
                        if (iy < 0 || iy >= NC) continue;
                        const bool ey = (dy == r) || (dy == -r);
                        for (int dx = -r; dx <= r; ++dx) {
                            if (!ez && !ey && dx != r && dx != -r) continue;
                            const int ix = icx + dx;
                            if (ix < 0 || ix >= NC) continue;
                            const int cid = (iz * NC + iy) * NC + ix;
                            const int cs = cstartL[cid];
                            const int ce = cstartL[cid + 1];
                            for (int k = cs; k < ce; ++k) {
                                const float4 c = cand4[k];
                                const float d = fmaf(-qz, c.z, fmaf(-qy, c.y, fmaf(-qx, c.x, c.w)));
                                if (d < best) {
                                    best = d; bk = k; borig = 0x7FFFFFFF;
                                } else if (d == best) {
                                    // rare: resolve first-occurrence via orig idx
                                    if (borig == 0x7FFFFFFF) borig = sorig[b * NL + bk];
                                    const int o = sorig[b * NL + k];
                                    borig = min(borig, o);
                                }
                            }
                        }
                    }
                }
            }
        }

        const int orig = (borig != 0x7FFFFFFF) ? borig : sorig[b * NL + bk];
        s_idx[tid] = b * NL + orig;         // global lr row
        __syncthreads();

        // Phase D: gather cols 67..197 for rows p0..p0+255.
        // 256*131 = 33536 elems = 131 slots * 256 thr; 12 batches of 11,
        // only the very last slot (s=131) dead. Decode: 256 = 1*131 + 125.
        {
            int rl = tid / 131;
            int c  = tid - rl * 131;
            for (int t = 0; t < 12; ++t) {
                int rs[11], cs_[11], ls[11];
                float vs[11];
#pragma unroll
                for (int k = 0; k < 11; ++k) {
                    rs[k] = rl; cs_[k] = c;
                    ls[k] = s_idx[rl < 256 ? rl : 255];
                    c += 125;
                    const int carry = (c >= 131) ? 1 : 0;
                    c -= carry ? 131 : 0;
                    rl += 1 + carry;
                }
#pragma unroll
                for (int k = 0; k < 11; ++k) {
                    const int cc = cs_[k];
                    const float* a = (cc < F_LR) ? x_lr   + ls[k] * F_LR + cc
                                                 : pos_lr + ls[k] * 3    + (cc - F_LR);
                    vs[k] = *a;
                }
#pragma unroll
                for (int k = 0; k < 11; ++k) {
                    if (t == 11 && k == 10) continue;   // dead slot s=131
                    out[(size_t)(p0 + rs[k]) * OUT_COLS + 67 + cs_[k]] = vs[k];
                }
            }
        }
    } else {
        // ----------------------------- copy role ----------------------------
        const int cb = blockIdx.x - 512;    // [0,512)
        const int r0 = cb << 8;             // 256 rows per block

#pragma unroll 4
        for (int e = tid; e < 256 * 67; e += 256) {
            const int rl = e / 67;
            const int c  = e - rl * 67;
            const int row = r0 + rl;
            const float v = (c < F_HR) ? x_hr[(row << 6) + c]
                                       : pos_hr[row * 3 + (c - F_HR)];
            out[row * OUT_COLS + c] = v;
        }

        const int R0 = NB * NH * OUT_COLS;  // 25,952,256
        const int Z  = NB * NH * 3;         // 393,216
        const int z0 = cb << 10;            // 1024 tail elems per block
#pragma unroll
        for (int e = tid; e < 1024; e += 256) {
            const int i = z0 + e;
            out[R0 + i] = (i < Z) ? 0.0f : (float)((i - Z) >> 14);  // NH = 2^14
        }
    }
}

extern "C" void kernel_launch(void* const* d_in, const int* in_sizes, int n_in,
                              void* d_out, int out_size, void* d_ws, size_t ws_size,
                              hipStream_t stream) {
    const float* x_hr   = (const float*)d_in[0];
    const float* pos_hr = (const float*)d_in[1];
    // d_in[2] = batch_hr (int32) — unused, batch is contiguous repeats
    const float* x_lr   = (const float*)d_in[3];
    const float* pos_lr = (const float*)d_in[4];
    // d_in[5] = batch_lr (int32) — unused

    float4* scand = (float4*)d_ws;                            // 256 KB
    int*    sorig = (int*)((char*)d_ws + 262144);             //  64 KB
    int*    cst   = (int*)((char*)d_ws + 327680);             // 128.1 KB
    float*  hdr   = (float*)((char*)d_ws + 458784);           // 384 B

    prep_kernel<<<dim3(8), dim3(256), 0, stream>>>(pos_lr, scand, sorig, cst, hdr);
    fused_kernel<<<dim3(1024), dim3(256), 0, stream>>>(
        pos_hr, pos_lr, x_hr, x_lr, scand, sorig, cst, hdr, (float*)d_out);
}

// Round 24
// 55.018 us; speedup vs baseline: 17.2893x; 17.2893x over previous
//
#include <hip/hip_runtime.h>

#define NB    8
#define NH    16384
#define NL    2048
#define F_HR  64
#define F_LR  128
#define OUT_COLS 198   // 64 + 3 + 128 + 3

// ---------------------------------------------------------------------------
// EXACT REVERT to R20 (best measured: 54.3 us). R23's grid-pruned search
// refuted: per-lane ring walk diverges on random queries (951 us, occ 4.5%,
// 2M bank-conflict cyc). Structural map (R8-R23): scan pinned ~40us by the
// {read-count x occupancy} web — read-optimal configs cap at 4 waves/SIMD
// (latency-exposed), wave-rich configs double reads (pipe-saturated); five
// within-wave pipelining levers null; pruning dies to divergence.
// Blocks [0,512): knn (M=4, 8 slices, value-only min3 scan + rescue) +
//   fused gather of cols 67..197 (overlaps gather under grid-wide scan).
// Blocks [512,768): idx-independent copy (cols 0..66, zeros, batch).
// LDS 51KB -> 3 blocks/CU.
// ---------------------------------------------------------------------------
__global__ __launch_bounds__(512, 4) void fused_kernel(
    const float* __restrict__ pos_hr,   // [NB*NH, 3]
    const float* __restrict__ pos_lr,   // [NB*NL, 3]
    const float* __restrict__ x_hr,     // [NB*NH, 64]
    const float* __restrict__ x_lr,     // [NB*NL, 128]
    float* __restrict__ out)
{
    __shared__ float4 cand[NL];         // 32 KiB (x, y, z, 0.5*|p|^2)
    __shared__ float  pval[8][256];     //  8 KiB per-slice min value
    __shared__ float  gminL[256];       //  1 KiB global min per point
    __shared__ int    winw[256];        //  1 KiB winning slice per point
    __shared__ short  plist[8][256];    //  4 KiB per-wave compacted points
    __shared__ float  phsx[256], phsy[256], phsz[256];   // 3 KiB staged ph
    __shared__ int    s_idx[256];       //  1 KiB final winner (global lr row)

    if (blockIdx.x < 512) {
        // ----------------------------- knn role -----------------------------
        const int b  = blockIdx.x >> 6;     // 64 blocks per batch
        const int p0 = blockIdx.x << 8;     // first global point of this block
        const int w  = threadIdx.x >> 6;    // wave id = candidate slice
        const int l  = threadIdx.x & 63;

        const float* pl = pos_lr + (size_t)b * NL * 3;
#pragma unroll
        for (int j = threadIdx.x; j < NL; j += 512) {
            float x = pl[j * 3 + 0];
            float y = pl[j * 3 + 1];
            float z = pl[j * 3 + 2];
            cand[j] = make_float4(x, y, z, 0.5f * ((x * x + y * y) + z * z));
        }

        float phx[4], phy[4], phz[4];
#pragma unroll
        for (int m = 0; m < 4; ++m) {
            const int pt = p0 + (m << 6) + l;
            phx[m] = pos_hr[pt * 3 + 0];
            phy[m] = pos_hr[pt * 3 + 1];
            phz[m] = pos_hr[pt * 3 + 2];
        }
        if (w == 0) {                        // stage ph for the rescue phase
#pragma unroll
            for (int m = 0; m < 4; ++m) {
                const int ptl = (m << 6) + l;
                phsx[ptl] = phx[m]; phsy[ptl] = phy[m]; phsz[ptl] = phz[m];
            }
        }
        __syncthreads();

        // Phase A: value-only scan, min3 accumulate, unroll 4 (8 reads/window)
        float best[4];
#pragma unroll
        for (int m = 0; m < 4; ++m) best[m] = 3.4e38f;

        const int base = w << 8;            // slice start (batch-local)
#pragma unroll 4
        for (int j = 0; j < 256; j += 2) {
            const float4 c0 = cand[base + j];
            const float4 c1 = cand[base + j + 1];
#pragma unroll
            for (int m = 0; m < 4; ++m) {
                float d0 = fmaf(-phz[m], c0.z, fmaf(-phy[m], c0.y, fmaf(-phx[m], c0.x, c0.w)));
                float d1 = fmaf(-phz[m], c1.z, fmaf(-phy[m], c1.y, fmaf(-phx[m], c1.x, c1.w)));
                best[m] = fminf(fminf(d0, d1), best[m]);   // -> v_min3_f32
            }
        }
#pragma unroll
        for (int m = 0; m < 4; ++m)
            pval[w][(m << 6) + l] = best[m];
        __syncthreads();

        // Phase B: per-point min over slices; strict < keeps lowest slice
        if (threadIdx.x < 256) {
            const int t = threadIdx.x;
            float g = pval[0][t]; int ww = 0;
#pragma unroll
            for (int q = 1; q < 8; ++q) {
                const float qv = pval[q][t];
                if (qv < g) { g = qv; ww = q; }
            }
            gminL[t] = g; winw[t] = ww;
        }
        __syncthreads();

        // Phase C: compact points this wave won, then index-rescue scan
        int cnt = 0;
#pragma unroll
        for (int m = 0; m < 4; ++m) {
            const int pt = (m << 6) + l;
            const bool pred = (winw[pt] == w);
            const unsigned long long mask = __ballot(pred);
            const int pos = __popcll(mask & ((1ull << l) - 1ull));
            if (pred) plist[w][cnt + pos] = (short)pt;
            cnt += __popcll(mask);
        }

        for (int i = 0; i < cnt; ++i) {
            const int pt = plist[w][i];
            const float qx = phsx[pt], qy = phsy[pt], qz = phsz[pt];
            const float g  = gminL[pt];
            int loc = 4;
#pragma unroll
            for (int k = 3; k >= 0; --k) {      // descending: final loc = lowest k
                const float4 c = cand[base + (l << 2) + k];
                const float d = fmaf(-qz, c.z, fmaf(-qy, c.y, fmaf(-qx, c.x, c.w)));
                if (d == g) loc = k;            // bit-exact recompute
            }
            const unsigned long long mk = __ballot(loc < 4);
            if (mk) {
                const int firstlane = __ffsll((unsigned long long)mk) - 1;
                const int locf = __shfl(loc, firstlane);
                if (l == 0)
                    s_idx[pt] = b * NL + base + (firstlane << 2) + locf;
            }
        }
        __syncthreads();

        // Phase D: gather cols 67..197 for rows p0..p0+255.
        // e-linear over 256*131 = 33536 elems; 66 = 6*11 iters; e = tid+n*512,
        // decode rl = e/131, c = e%131 incrementally (512 = 3*131 + 119).
        {
            const int tid = threadIdx.x;
            int rl = tid / 131;
            int c  = tid - rl * 131;
            for (int t = 0; t < 11; ++t) {
                int rs[6], cs[6], ls[6];
                float vs[6];
#pragma unroll
                for (int k = 0; k < 6; ++k) {
                    rs[k] = rl; cs[k] = c;
                    ls[k] = s_idx[rl < 256 ? rl : 255];
                    c += 119;
                    const int carry = (c >= 131) ? 1 : 0;
                    c -= carry ? 131 : 0;
                    rl += 3 + carry;
                }
#pragma unroll
                for (int k = 0; k < 6; ++k) {
                    const int cc = cs[k];
                    const float* a = (cc < F_LR) ? x_lr   + ls[k] * F_LR + cc
                                                 : pos_lr + ls[k] * 3    + (cc - F_LR);
                    vs[k] = *a;
                }
#pragma unroll
                for (int k = 0; k < 6; ++k) {
                    if (t == 10 && k == 5 && tid + 33280 >= 33536) continue;  // guard
                    out[(size_t)(p0 + rs[k]) * OUT_COLS + 67 + cs[k]] = vs[k];
                }
            }
        }
    } else {
        // ----------------------------- copy role ----------------------------
        const int cb = blockIdx.x - 512;    // [0,256)
        const int r0 = cb << 9;             // 512 rows per block

#pragma unroll 4
        for (int e = threadIdx.x; e < 512 * 67; e += 512) {
            const int rl  = e / 67;
            const int c   = e - rl * 67;
            const int row = r0 + rl;
            const float v = (c < F_HR) ? x_hr[(row << 6) + c]
                                       : pos_hr[row * 3 + (c - F_HR)];
            out[row * OUT_COLS + c] = v;
        }

        const int R0 = NB * NH * OUT_COLS;  // 25,952,256
        const int Z  = NB * NH * 3;         // 393,216
        const int z0 = cb << 11;
#pragma unroll
        for (int e = threadIdx.x; e < 2048; e += 512) {
            const int i = z0 + e;
            out[R0 + i] = (i < Z) ? 0.0f : (float)((i - Z) >> 14);  // NH = 2^14
        }
    }
}

extern "C" void kernel_launch(void* const* d_in, const int* in_sizes, int n_in,
                              void* d_out, int out_size, void* d_ws, size_t ws_size,
                              hipStream_t stream) {
    const float* x_hr   = (const float*)d_in[0];
    const float* pos_hr = (const float*)d_in[1];
    // d_in[2] = batch_hr (int32) — unused, batch is contiguous repeats
    const float* x_lr   = (const float*)d_in[3];
    const float* pos_lr = (const float*)d_in[4];
    // d_in[5] = batch_lr (int32) — unused

    fused_kernel<<<dim3(768), dim3(512), 0, stream>>>(
        pos_hr, pos_lr, x_hr, x_lr, (float*)d_out);
}